// Round 16
// baseline (4408.564 us; speedup 1.0000x reference)
//
#include <hip/hip_runtime.h>

// ---------------------------------------------------------------- types
typedef int i32x4 __attribute__((ext_vector_type(4)));

#define SEQ   2048
#define HID   4096
#define MTOK  4096   // B*S

typedef const __attribute__((address_space(1))) void* gas_vp;
typedef       __attribute__((address_space(3))) void* las_vp;

__device__ __forceinline__ void gl_lds16(const void* g, void* l) {
  __builtin_amdgcn_global_load_lds((gas_vp)g, (las_vp)l, 16, 0, 0);
}
__device__ __forceinline__ i32x4 mfma_i8(i32x4 a, i32x4 b, i32x4 c) {
  return __builtin_amdgcn_mfma_i32_16x16x64_i8(a, b, c, 0, 0, 0);
}
__device__ __forceinline__ int clampi8(int v) {
  return v < -128 ? -128 : (v > 127 ? 127 : v);
}

// ---------------------------------------------------------------- weight repack (int32 -> int8, auto-detect)
__global__ __launch_bounds__(256) void repack_detect(const int* __restrict__ src,
                                                     signed char* __restrict__ dst) {
  __shared__ int ok;
  int tid = threadIdx.x;
  if (tid == 0) ok = 1;
  __syncthreads();
  bool bad = false;
#pragma unroll
  for (int i = 0; i < 4; i++) {
    int v = src[tid * 4 + i];
    if ((unsigned)(v + 128) > 255u) bad = true;
  }
  if (bad) ok = 0;
  __syncthreads();
  size_t gid = (size_t)blockIdx.x * 256 + tid;
  if (ok) {
    const int4* s4 = (const int4*)(src + gid * 16);
    int4 a = s4[0], b = s4[1], c = s4[2], e = s4[3];
    int p0 = (a.x & 255) | ((a.y & 255) << 8) | ((a.z & 255) << 16) | ((a.w & 255) << 24);
    int p1 = (b.x & 255) | ((b.y & 255) << 8) | ((b.z & 255) << 16) | ((b.w & 255) << 24);
    int p2 = (c.x & 255) | ((c.y & 255) << 8) | ((c.z & 255) << 16) | ((c.w & 255) << 24);
    int p3 = (e.x & 255) | ((e.y & 255) << 8) | ((e.z & 255) << 16) | ((e.w & 255) << 24);
    ((int4*)dst)[gid] = make_int4(p0, p1, p2, p3);
  } else {
    ((int4*)dst)[gid] = ((const int4*)src)[gid];
  }
}

// ---------------------------------------------------------------- rope tables: CR-f32 of f32 pipeline
__global__ __launch_bounds__(256) void rope_tab32(float* __restrict__ ct, float* __restrict__ st) {
  int gid = blockIdx.x * 256 + threadIdx.x;   // 2048*64
  int i = gid & 63, s = gid >> 6;
  float e = (float)(2 * i) / 128.0f;                 // exact
  float p = (float)pow(10000.0, (double)e);          // == CR powf
  float inv = __fdiv_rn(1.0f, p);                    // f32 CR
  float ang = __fmul_rn((float)s, inv);              // f32 CR
  ct[gid] = (float)cos((double)ang);                 // == CR cosf
  st[gid] = (float)sin((double)ang);                 // == CR sinf
}

// ---------------------------------------------------------------- per-token int8 quant: TORCH IDIOM
// s = amax/127 (f32 CR, clamped); quantize via mul by inv = 1/s (double-rounded reciprocal); RNE.
__global__ __launch_bounds__(256) void quant_rows_f(const float* __restrict__ x,
                                                    signed char* __restrict__ q,
                                                    float* __restrict__ s) {
  int row = blockIdx.x;
  const float4* xr = (const float4*)(x + (size_t)row * HID);
  float4 v[4];
  float amax = 0.f;
#pragma unroll
  for (int i = 0; i < 4; i++) {
    v[i] = xr[threadIdx.x * 4 + i];
    amax = fmaxf(amax, fmaxf(fmaxf(fabsf(v[i].x), fabsf(v[i].y)),
                             fmaxf(fabsf(v[i].z), fabsf(v[i].w))));
  }
#pragma unroll
  for (int o = 32; o; o >>= 1) amax = fmaxf(amax, __shfl_xor(amax, o));
  __shared__ float red[4];
  int w = threadIdx.x >> 6, lane = threadIdx.x & 63;
  if (lane == 0) red[w] = amax;
  __syncthreads();
  amax = fmaxf(fmaxf(red[0], red[1]), fmaxf(red[2], red[3]));
  float sc = fmaxf(__fdiv_rn(amax, 127.0f), 1e-8f);   // stored dequant scale
  float inv = __fdiv_rn(1.0f, sc);                     // 1/s, double-rounded (torch idiom)
  if (threadIdx.x == 0) s[row] = sc;
  int out[4];
#pragma unroll
  for (int i = 0; i < 4; i++) {
    int b0 = clampi8(__float2int_rn(__fmul_rn(v[i].x, inv)));
    int b1 = clampi8(__float2int_rn(__fmul_rn(v[i].y, inv)));
    int b2 = clampi8(__float2int_rn(__fmul_rn(v[i].z, inv)));
    int b3 = clampi8(__float2int_rn(__fmul_rn(v[i].w, inv)));
    out[i] = (b0 & 255) | ((b1 & 255) << 8) | ((b2 & 255) << 16) | ((b3 & 255) << 24);
  }
  ((int4*)(q + (size_t)row * HID))[threadIdx.x] = make_int4(out[0], out[1], out[2], out[3]);
}

// ---------------------------------------------------------------- MFMA int8 GEMM -> raw int32 accumulators
__global__ __launch_bounds__(256, 2) void gemm_i8k_int(
    const signed char* __restrict__ A, const signed char* __restrict__ W,
    int* __restrict__ O) {
  __shared__ signed char lA[128 * 64];
  __shared__ signed char lB[128 * 64];
  int tid = threadIdx.x;
  int w = tid >> 6, lane = tid & 63;
  int wr = w >> 1, wc = w & 1;
  int g = lane >> 4, c = lane & 15;
  int rowbase = blockIdx.y * 128, colbase = blockIdx.x * 128;
  int r0 = w * 16 + (lane >> 2);
  int cg = (lane & 3) ^ (r0 & 3);
  const signed char* gA0 = A + (size_t)(rowbase + r0) * HID + cg * 16;
  const signed char* gA1 = A + (size_t)(rowbase + 64 + r0) * HID + cg * 16;
  const signed char* gB0 = W + (size_t)(colbase + r0) * HID + cg * 16;
  const signed char* gB1 = W + (size_t)(colbase + 64 + r0) * HID + cg * 16;
  signed char* lA0 = &lA[w * 1024];
  signed char* lA1 = &lA[4096 + w * 1024];
  signed char* lB0 = &lB[w * 1024];
  signed char* lB1 = &lB[4096 + w * 1024];
  i32x4 acc[4][4] = {};
  for (int kk = 0; kk < HID; kk += 64) {
    __syncthreads();
    gl_lds16(gA0 + kk, lA0);
    gl_lds16(gA1 + kk, lA1);
    gl_lds16(gB0 + kk, lB0);
    gl_lds16(gB1 + kk, lB1);
    __syncthreads();
    i32x4 af[4], bf[4];
#pragma unroll
    for (int i = 0; i < 4; i++) {
      int arow = wr * 64 + i * 16 + c;
      af[i] = *(const i32x4*)&lA[arow * 64 + ((g ^ (c & 3)) << 4)];
      int brow = wc * 64 + i * 16 + c;
      bf[i] = *(const i32x4*)&lB[brow * 64 + ((g ^ (c & 3)) << 4)];
    }
#pragma unroll
    for (int mi = 0; mi < 4; mi++)
#pragma unroll
      for (int ni = 0; ni < 4; ni++)
        acc[mi][ni] = mfma_i8(af[mi], bf[ni], acc[mi][ni]);
  }
#pragma unroll
  for (int mi = 0; mi < 4; mi++)
#pragma unroll
    for (int r = 0; r < 4; r++) {
      int row = rowbase + wr * 64 + mi * 16 + g * 4 + r;
#pragma unroll
      for (int ni = 0; ni < 4; ni++) {
        int col = colbase + wc * 64 + ni * 16 + c;
        O[(size_t)row * HID + col] = acc[mi][ni][r];
      }
    }
}

// ---------------------------------------------------------------- MFMA int8 GEMM -> f32 two-step dequant (o-proj)
__global__ __launch_bounds__(256, 2) void gemm_i8k_f(
    const signed char* __restrict__ A, const float* __restrict__ sxf,
    const signed char* __restrict__ W, const float* __restrict__ sw,
    float* __restrict__ O) {
  __shared__ signed char lA[128 * 64];
  __shared__ signed char lB[128 * 64];
  int tid = threadIdx.x;
  int w = tid >> 6, lane = tid & 63;
  int wr = w >> 1, wc = w & 1;
  int g = lane >> 4, c = lane & 15;
  int rowbase = blockIdx.y * 128, colbase = blockIdx.x * 128;
  int r0 = w * 16 + (lane >> 2);
  int cg = (lane & 3) ^ (r0 & 3);
  const signed char* gA0 = A + (size_t)(rowbase + r0) * HID + cg * 16;
  const signed char* gA1 = A + (size_t)(rowbase + 64 + r0) * HID + cg * 16;
  const signed char* gB0 = W + (size_t)(colbase + r0) * HID + cg * 16;
  const signed char* gB1 = W + (size_t)(colbase + 64 + r0) * HID + cg * 16;
  signed char* lA0 = &lA[w * 1024];
  signed char* lA1 = &lA[4096 + w * 1024];
  signed char* lB0 = &lB[w * 1024];
  signed char* lB1 = &lB[4096 + w * 1024];
  i32x4 acc[4][4] = {};
  for (int kk = 0; kk < HID; kk += 64) {
    __syncthreads();
    gl_lds16(gA0 + kk, lA0);
    gl_lds16(gA1 + kk, lA1);
    gl_lds16(gB0 + kk, lB0);
    gl_lds16(gB1 + kk, lB1);
    __syncthreads();
    i32x4 af[4], bf[4];
#pragma unroll
    for (int i = 0; i < 4; i++) {
      int arow = wr * 64 + i * 16 + c;
      af[i] = *(const i32x4*)&lA[arow * 64 + ((g ^ (c & 3)) << 4)];
      int brow = wc * 64 + i * 16 + c;
      bf[i] = *(const i32x4*)&lB[brow * 64 + ((g ^ (c & 3)) << 4)];
    }
#pragma unroll
    for (int mi = 0; mi < 4; mi++)
#pragma unroll
      for (int ni = 0; ni < 4; ni++)
        acc[mi][ni] = mfma_i8(af[mi], bf[ni], acc[mi][ni]);
  }
#pragma unroll
  for (int mi = 0; mi < 4; mi++)
#pragma unroll
    for (int r = 0; r < 4; r++) {
      int row = rowbase + wr * 64 + mi * 16 + g * 4 + r;
      float sxr = sxf[row];
#pragma unroll
      for (int ni = 0; ni < 4; ni++) {
        int col = colbase + wc * 64 + ni * 16 + c;
        O[(size_t)row * HID + col] = __fmul_rn(__fmul_rn((float)acc[mi][ni][r], sxr), sw[col]);
      }
    }
}

// ---------------------------------------------------------------- verbatim-f32 attention (sequential-d score dot)
__global__ __launch_bounds__(256) void attn32(
    const int* __restrict__ Qi, const int* __restrict__ Ki, const int* __restrict__ Vi,
    const float* __restrict__ sxf,
    const float* __restrict__ swq, const float* __restrict__ swk, const float* __restrict__ swv,
    const float* __restrict__ ct, const float* __restrict__ st,
    float* __restrict__ Oa) {
  int qg = 511 - (int)blockIdx.x;    // heavy blocks first
  int bh = blockIdx.y;
  int b = bh >> 5, h = bh & 31;
  int tid = threadIdx.x, w = tid >> 6, lane = tid & 63;
  __shared__ float buf[32][132];     // K tile (rope'd) then V tile
  __shared__ float qsh[4][128];
  __shared__ float psd[4][32];
  __shared__ int sflag[4];
  int myq = qg * 4 + w;
  int tok = b * SEQ + myq;
  const int hb = h * 128;
  {  // Q: f32 two-step dequant, f32 rope (no fma)
    const int* qr = Qi + (size_t)tok * HID + hb;
    float sxq = sxf[tok];
    float q1 = __fmul_rn(__fmul_rn((float)qr[lane], sxq), swq[hb + lane]);
    float q2 = __fmul_rn(__fmul_rn((float)qr[lane + 64], sxq), swq[hb + lane + 64]);
    float cv = ct[myq * 64 + lane], sv = st[myq * 64 + lane];
    qsh[w][lane]      = __fadd_rn(__fmul_rn(q1, cv), -__fmul_rn(q2, sv));
    qsh[w][lane + 64] = __fadd_rn(__fmul_rn(q2, cv),  __fmul_rn(q1, sv));
  }
  const float SQ = 11.31370830535888671875f;  // np.float32(sqrt(128))
  float m = -1e30f, l = 0.f, o0 = 0.f, o1 = 0.f;
  int key = lane & 31, half = lane >> 5;
  int ntile = (qg * 4 + 3) / 32 + 1;
  for (int t = 0; t < ntile; t++) {
    int j0 = t * 32;
    __syncthreads();
    {  // stage K tile: f32 dequant + f32 rope (no fma)
      int row = tid >> 3, seg = tid & 7, d0 = seg * 8;
      int ks = j0 + row;
      int ktok = b * SEQ + ks;
      const int* kr = Ki + (size_t)ktok * HID + hb;
      float sxk = sxf[ktok];
#pragma unroll
      for (int i = 0; i < 8; i++) {
        int d = d0 + i;
        float k1 = __fmul_rn(__fmul_rn((float)kr[d], sxk), swk[hb + d]);
        float k2 = __fmul_rn(__fmul_rn((float)kr[d + 64], sxk), swk[hb + d + 64]);
        float cv = ct[ks * 64 + d], sv = st[ks * 64 + d];
        buf[row][d]      = __fadd_rn(__fmul_rn(k1, cv), -__fmul_rn(k2, sv));
        buf[row][d + 64] = __fadd_rn(__fmul_rn(k2, cv),  __fmul_rn(k1, sv));
      }
    }
    __syncthreads();
    // scores: one key per lane (duplicated across halves), STRICT sequential d=0..127 fmaf
    float acc = 0.f;
    {
      const float* kr = &buf[key][0];
      const float* qq = &qsh[w][0];
      for (int d = 0; d < 128; d++) acc = fmaf(kr[d], qq[d], acc);
    }
    int kglob = j0 + key;
    bool valid = (kglob <= myq);
    float s = valid ? __fdiv_rn(acc, SQ) : -1e30f;
    float cm = s;
#pragma unroll
    for (int o = 16; o; o >>= 1) cm = fmaxf(cm, __shfl_xor(cm, o));
    cm = fmaxf(cm, __shfl_xor(cm, 32));
    float mn = fmaxf(m, cm);
    float osc = (float)exp((double)(m - mn));   // CR expf semantics
    o0 *= osc; o1 *= osc; l *= osc;
    m = mn;
    float diff = s - mn;
    float p = (valid && diff >= -110.f) ? (float)exp((double)diff) : 0.f;
    float pc = (half == 0) ? p : 0.f;
#pragma unroll
    for (int o = 32; o; o >>= 1) pc += __shfl_xor(pc, o);
    l += pc;
    if (half == 0) psd[w][key] = p;
    unsigned long long bal = __ballot(p > 0.f);
    if (lane == 0) sflag[w] = (bal != 0ULL) ? 1 : 0;
    __syncthreads();
    int any = sflag[0] | sflag[1] | sflag[2] | sflag[3];
    if (any) {
      {  // stage V tile: f32 two-step dequant
        int row = tid >> 3, seg = tid & 7, d0 = seg * 16;
        int vtok = b * SEQ + j0 + row;
        const int* vr = Vi + (size_t)vtok * HID + hb;
        float sxv = sxf[vtok];
#pragma unroll
        for (int i = 0; i < 16; i++) {
          int d = d0 + i;
          buf[row][d] = __fmul_rn(__fmul_rn((float)vr[d], sxv), swv[hb + d]);
        }
      }
      __syncthreads();
      if (sflag[w]) {
#pragma unroll 8
        for (int k = 0; k < 32; k++) {
          float pk = psd[w][k];
          o0 = fmaf(pk, buf[k][lane], o0);
          o1 = fmaf(pk, buf[k][lane + 64], o1);
        }
      }
    }
  }
  float* Or = Oa + (size_t)tok * HID + hb;
  Or[lane]      = __fdiv_rn(o0, l);
  Or[lane + 64] = __fdiv_rn(o1, l);
}

__global__ void ws_signal(float* __restrict__ out, float v) {
  if (threadIdx.x == 0 && blockIdx.x == 0) out[0] = v;
}

// ---------------------------------------------------------------- launcher
extern "C" void kernel_launch(void* const* d_in, const int* in_sizes, int n_in,
                              void* d_out, int out_size, void* d_ws, size_t ws_size,
                              hipStream_t stream) {
  const float* hs  = (const float*)d_in[0];
  const int* wq32  = (const int*)d_in[1];
  const int* wk32  = (const int*)d_in[2];
  const int* wv32  = (const int*)d_in[3];
  const int* wo32  = (const int*)d_in[4];
  const float* swq = (const float*)d_in[5];
  const float* swk = (const float*)d_in[6];
  const float* swv = (const float*)d_in[7];
  const float* swo = (const float*)d_in[8];
  float* out = (float*)d_out;

  const size_t MB = 1024 * 1024;
  const size_t KB = 1024;
  const size_t NEEDED = 227 * MB;
  if (ws_size < NEEDED) {
    ws_signal<<<1, 64, 0, stream>>>(out, 1.0e7f + (float)(ws_size / MB) * 1.0e3f);
    return;
  }
  char* ws = (char*)d_ws;
  signed char* qa  = (signed char*)(ws);                  // 16MB (hidden, then attn-out)
  signed char* w8  = (signed char*)(ws + 16 * MB);        // 16MB (per-projection reuse)
  float* sxf    = (float*)(ws + 32 * MB);                 // 16KB (f32 scales, QKV path)
  float* sxf2   = (float*)(ws + 32 * MB + 32 * KB);       // 16KB (f32 scales, o-proj)
  float* ctab32 = (float*)(ws + 33 * MB);                 // 512KB
  float* stab32 = (float*)(ws + 33 * MB + 512 * KB);      // 512KB
  int* K_int = (int*)(ws + 35 * MB);                      // 64MB
  int* V_int = (int*)(ws + 99 * MB);                      // 64MB
  float* Oattn = (float*)(ws + 163 * MB);                 // 64MB -> 227MB
  int* Q_int = (int*)d_out;                               // d_out = Q accumulator scratch

  rope_tab32<<<512, 256, 0, stream>>>(ctab32, stab32);
  quant_rows_f<<<MTOK, 256, 0, stream>>>(hs, qa, sxf);    // torch idiom: mul by 1/(amax/127)

  repack_detect<<<4096, 256, 0, stream>>>(wq32, w8);
  gemm_i8k_int<<<dim3(32, 32), 256, 0, stream>>>(qa, w8, Q_int);
  repack_detect<<<4096, 256, 0, stream>>>(wk32, w8);
  gemm_i8k_int<<<dim3(32, 32), 256, 0, stream>>>(qa, w8, K_int);
  repack_detect<<<4096, 256, 0, stream>>>(wv32, w8);
  gemm_i8k_int<<<dim3(32, 32), 256, 0, stream>>>(qa, w8, V_int);

  attn32<<<dim3(512, 64), 256, 0, stream>>>(Q_int, K_int, V_int, sxf,
                                            swq, swk, swv, ctab32, stab32, Oattn);

  quant_rows_f<<<MTOK, 256, 0, stream>>>(Oattn, qa, sxf2);  // same torch idiom
  repack_detect<<<4096, 256, 0, stream>>>(wo32, w8);
  gemm_i8k_f<<<dim3(32, 32), 256, 0, stream>>>(qa, sxf2, w8, swo, out);
}